// Round 1
// baseline (327.978 us; speedup 1.0000x reference)
//
#include <hip/hip_runtime.h>
#include <cstdint>
#include <cstddef>

// ---------------------------------------------------------------------------
// GatedLatticeLayer on MI355X.
// B=16 S=512 W=5 H=512 E=256 V=100000.  MROWS = B*S = 8192.
//
// Restructured math (see round-0 analysis):
//   QKV  = X @ W_hidden + b_hidden            (8192 x 1536)  [q|hk|hv]
//   P    = q @ [Wk_b^T | Wk_m^T | Wk_e^T | bk_b bk_m bk_e]   (8192 x 771, pad 896)
//   lattice score(t,w) = g_t * (P_t . emb[idx] + P[768+t])
//   ebar_t = sum_w weight * g_t * emb[idx]    (8192 x 768, bf16)
//   out = w0*hv + sum_t alpha_t*bv_t + Ebar @ [Wv_b;Wv_m;Wv_e]
// Precision: q,hk columns via split-bf16 (3-term MFMA) because s0=q.hk feeds
// softmax near-ties; everything else plain bf16 MFMA / fp32 VALU.
// ---------------------------------------------------------------------------

typedef unsigned short u16;
typedef __attribute__((ext_vector_type(8))) short short8;
typedef __attribute__((ext_vector_type(8))) __bf16 bf16x8;
typedef __attribute__((ext_vector_type(4))) float f32x4;

#define MROWS 8192
#define SS 512

static __device__ __forceinline__ u16 f2bf(float x) {
  uint32_t u = __builtin_bit_cast(uint32_t, x);
  u += 0x7FFFu + ((u >> 16) & 1u);
  return (u16)(u >> 16);
}
static __device__ __forceinline__ float bf2f(u16 h) {
  return __builtin_bit_cast(float, (uint32_t)h << 16);
}
static __device__ __forceinline__ float sigm(float x) { return 1.f / (1.f + __expf(-x)); }

// ---------------- prep: X -> hi/lo bf16 ------------------------------------
__global__ void split_x_kernel(const float* __restrict__ X, u16* __restrict__ hi,
                               u16* __restrict__ lo, int n4) {
  int i = blockIdx.x * blockDim.x + threadIdx.x;
  if (i >= n4) return;
  float4 x = ((const float4*)X)[i];
  ushort4 h, l;
  h.x = f2bf(x.x); l.x = f2bf(x.x - bf2f(h.x));
  h.y = f2bf(x.y); l.y = f2bf(x.y - bf2f(h.y));
  h.z = f2bf(x.z); l.z = f2bf(x.z - bf2f(h.z));
  h.w = f2bf(x.w); l.w = f2bf(x.w - bf2f(h.w));
  ((ushort4*)hi)[i] = h;
  ((ushort4*)lo)[i] = l;
}

// ---------------- prep: W_hidden (512x1536) -> transposed hi/lo (1536x512) --
__global__ void transpose_split_wh(const float* __restrict__ Wsrc,
                                   u16* __restrict__ hi, u16* __restrict__ lo) {
  __shared__ float tile[64][65];
  int k0 = blockIdx.x * 64;   // K rows (512)
  int n0 = blockIdx.y * 64;   // N cols (1536)
  int t = threadIdx.x;
#pragma unroll
  for (int i = 0; i < 16; i++) {
    int li = i * 256 + t; int r = li >> 6, c = li & 63;
    tile[r][c] = Wsrc[(size_t)(k0 + r) * 1536 + n0 + c];
  }
  __syncthreads();
#pragma unroll
  for (int i = 0; i < 16; i++) {
    int li = i * 256 + t; int r = li >> 6, c = li & 63;
    float v = tile[c][r];               // = Wsrc[k0+c][n0+r]
    size_t o = (size_t)(n0 + r) * 512 + k0 + c;
    u16 h = f2bf(v);
    hi[o] = h;
    lo[o] = f2bf(v - bf2f(h));
  }
}

// ---------------- prep: WkT (896 x 512 bf16) --------------------------------
// rows 0..767: W_t[c][0..511]; rows 768..770: b_t[0..511]; rest zero.
__global__ void build_wkT(const float* __restrict__ Wb, const float* __restrict__ Wm,
                          const float* __restrict__ We, const float* __restrict__ bb,
                          const float* __restrict__ bm, const float* __restrict__ be,
                          u16* __restrict__ WkT) {
  int tid = blockIdx.x * blockDim.x + threadIdx.x;
  if (tid >= 896 * 128) return;
  int n = tid >> 7;
  int kq = (tid & 127) * 4;
  float4 v;
  if (n < 768) {
    int ty = n >> 8, c = n & 255;
    const float* src = (ty == 0 ? Wb : ty == 1 ? Wm : We) + (size_t)c * 1024 + kq;
    v = *(const float4*)src;
  } else if (n < 771) {
    int ty = n - 768;
    const float* src = (ty == 0 ? bb : ty == 1 ? bm : be) + kq;
    v = *(const float4*)src;
  } else {
    v = make_float4(0.f, 0.f, 0.f, 0.f);
  }
  ushort4 h; h.x = f2bf(v.x); h.y = f2bf(v.y); h.z = f2bf(v.z); h.w = f2bf(v.w);
  ((ushort4*)WkT)[tid] = h;
}

// ---------------- prep: WvT (512 x 768 bf16): WvT[n][t*256+c]=W_t[c][512+n] -
__global__ void build_wvT(const float* __restrict__ Wb, const float* __restrict__ Wm,
                          const float* __restrict__ We, u16* __restrict__ WvT) {
  __shared__ float tile[64][65];
  int ty = blockIdx.z;
  const float* Wsrc = ty == 0 ? Wb : ty == 1 ? Wm : We;
  int c0 = blockIdx.x * 64;   // E rows (256)
  int n0 = blockIdx.y * 64;   // H cols (512)
  int t = threadIdx.x;
#pragma unroll
  for (int i = 0; i < 16; i++) {
    int li = i * 256 + t; int r = li >> 6, c = li & 63;
    tile[r][c] = Wsrc[(size_t)(c0 + r) * 1024 + 512 + n0 + c];
  }
  __syncthreads();
#pragma unroll
  for (int i = 0; i < 16; i++) {
    int li = i * 256 + t; int r = li >> 6, c = li & 63;
    float v = tile[c][r];               // = Wsrc[c0+c][512+n0+r]
    WvT[(size_t)(n0 + r) * 768 + ty * 256 + c0 + c] = f2bf(v);
  }
}

// ---------------- lmr = X @ W_gate + b_gate  (8192 x 9) ---------------------
__global__ __launch_bounds__(256) void lmr_kernel(const float* __restrict__ X,
                                                  const float* __restrict__ Wg,
                                                  const float* __restrict__ bg,
                                                  float* __restrict__ lmr) {
  __shared__ float wg[512 * 9];
  int t = threadIdx.x;
  for (int i = t; i < 4608; i += 256) wg[i] = Wg[i];
  __syncthreads();
  int lane = t & 63, wid = t >> 6;
  int pos = blockIdx.x * 4 + wid;
  const float* x = X + (size_t)pos * 512 + lane * 8;
  float4 x0 = *(const float4*)x;
  float4 x1 = *(const float4*)(x + 4);
  float xs[8] = {x0.x, x0.y, x0.z, x0.w, x1.x, x1.y, x1.z, x1.w};
  float p[9];
#pragma unroll
  for (int c = 0; c < 9; c++) p[c] = 0.f;
  const float* wrow = wg + (lane * 8) * 9;
#pragma unroll
  for (int j = 0; j < 8; j++)
#pragma unroll
    for (int c = 0; c < 9; c++) p[c] += xs[j] * wrow[j * 9 + c];
#pragma unroll
  for (int c = 0; c < 9; c++)
#pragma unroll
    for (int o = 32; o > 0; o >>= 1) p[c] += __shfl_xor(p[c], o);
  if (lane == 0) {
#pragma unroll
    for (int c = 0; c < 9; c++) lmr[(size_t)pos * 9 + c] = p[c] + bg[c];
  }
}

// ---------------- gates (8192 x 3) ------------------------------------------
__global__ void gates_kernel(const float* __restrict__ lmr, const int* __restrict__ masks,
                             float* __restrict__ gates) {
  int pos = blockIdx.x * blockDim.x + threadIdx.x;
  if (pos >= MROWS) return;
  int s = pos & (SS - 1);
  float g0, g1, g2;
  if (masks[pos] == 0) {
    g0 = g1 = g2 = 0.f;
  } else if (s == 0 || s == SS - 1) {
    g0 = 1.f; g1 = 0.f; g2 = 1.f;
  } else {
    const float* l0 = lmr + (size_t)(pos - 1) * 9;
    const float* l1 = lmr + (size_t)pos * 9;
    const float* l2 = lmr + (size_t)(pos + 1) * 9;
    g0 = sigm(l0[0] + l1[3] + l2[6]);
    g1 = sigm(l0[1] + l1[4] + l2[7]);
    g2 = sigm(l0[2] + l1[5] + l2[8]);
  }
  gates[(size_t)pos * 3 + 0] = g0;
  gates[(size_t)pos * 3 + 1] = g1;
  gates[(size_t)pos * 3 + 2] = g2;
}

// ---------------- MFMA GEMM: C[m, col0+n] (+=) A(m,K) @ Bt(n,K)^T + bias ----
// 128x128 block tile, 4 waves (2x2), each wave 4x4 of 16x16x32 bf16 MFMA.
template <bool SPLIT, bool ADDOUT, bool WRITE_QBF, bool HAS_BIAS>
__global__ __launch_bounds__(256) void gemm_mfma(
    const u16* __restrict__ Ahi, const u16* __restrict__ Alo,
    const u16* __restrict__ Bhi, const u16* __restrict__ Blo,
    const float* __restrict__ bias, float* __restrict__ C, u16* __restrict__ Qbf,
    int Kdim, int ldC, int col0) {
  __shared__ __align__(16) u16 As_hi[128 * 32];
  __shared__ __align__(16) u16 Bs_hi[128 * 32];
  __shared__ __align__(16) u16 As_lo[SPLIT ? 128 * 32 : 8];
  __shared__ __align__(16) u16 Bs_lo[SPLIT ? 128 * 32 : 8];

  const int t = threadIdx.x;
  const int lane = t & 63;
  const int wid = t >> 6;
  const int m0 = blockIdx.x * 128;
  const int n0 = blockIdx.y * 128;
  const int wm = (wid & 1) * 64;
  const int wn = (wid >> 1) * 64;
  const int fr = lane & 15;
  const int kq = (lane >> 4) * 8;

  f32x4 acc[4][4];
#pragma unroll
  for (int i = 0; i < 4; i++)
#pragma unroll
    for (int j = 0; j < 4; j++) acc[i][j] = (f32x4){0.f, 0.f, 0.f, 0.f};

  for (int k0 = 0; k0 < Kdim; k0 += 32) {
    __syncthreads();
#pragma unroll
    for (int p = 0; p < 2; p++) {
      int li = p * 256 + t;
      int row = li >> 2;
      int so = (li & 3) * 8;
      size_t ga = (size_t)(m0 + row) * Kdim + k0 + so;
      size_t gb = (size_t)(n0 + row) * Kdim + k0 + so;
      int ls = row * 32 + so;
      *(uint4*)&As_hi[ls] = *(const uint4*)&Ahi[ga];
      *(uint4*)&Bs_hi[ls] = *(const uint4*)&Bhi[gb];
      if constexpr (SPLIT) {
        *(uint4*)&As_lo[ls] = *(const uint4*)&Alo[ga];
        *(uint4*)&Bs_lo[ls] = *(const uint4*)&Blo[gb];
      }
    }
    __syncthreads();
    short8 ah[4], bh[4], al[4], bl[4];
#pragma unroll
    for (int i = 0; i < 4; i++) {
      ah[i] = *(const short8*)&As_hi[(wm + i * 16 + fr) * 32 + kq];
      bh[i] = *(const short8*)&Bs_hi[(wn + i * 16 + fr) * 32 + kq];
      if constexpr (SPLIT) {
        al[i] = *(const short8*)&As_lo[(wm + i * 16 + fr) * 32 + kq];
        bl[i] = *(const short8*)&Bs_lo[(wn + i * 16 + fr) * 32 + kq];
      }
    }
#pragma unroll
    for (int mt = 0; mt < 4; mt++)
#pragma unroll
      for (int nt = 0; nt < 4; nt++) {
        acc[mt][nt] = __builtin_amdgcn_mfma_f32_16x16x32_bf16(
            __builtin_bit_cast(bf16x8, ah[mt]), __builtin_bit_cast(bf16x8, bh[nt]),
            acc[mt][nt], 0, 0, 0);
        if constexpr (SPLIT) {
          acc[mt][nt] = __builtin_amdgcn_mfma_f32_16x16x32_bf16(
              __builtin_bit_cast(bf16x8, al[mt]), __builtin_bit_cast(bf16x8, bh[nt]),
              acc[mt][nt], 0, 0, 0);
          acc[mt][nt] = __builtin_amdgcn_mfma_f32_16x16x32_bf16(
              __builtin_bit_cast(bf16x8, ah[mt]), __builtin_bit_cast(bf16x8, bl[nt]),
              acc[mt][nt], 0, 0, 0);
        }
      }
  }

  const int r0 = (lane >> 4) * 4;
#pragma unroll
  for (int mt = 0; mt < 4; mt++) {
#pragma unroll
    for (int nt = 0; nt < 4; nt++) {
      int col = col0 + n0 + wn + nt * 16 + fr;
      float bv = 0.f;
      if constexpr (HAS_BIAS) bv = bias[col];
#pragma unroll
      for (int r = 0; r < 4; r++) {
        int row = m0 + wm + mt * 16 + r0 + r;
        size_t off = (size_t)row * ldC + col;
        float v = acc[mt][nt][r] + bv;
        if constexpr (ADDOUT) v += C[off];
        C[off] = v;
        if constexpr (WRITE_QBF) {
          if (col < 512) Qbf[(size_t)row * 512 + col] = f2bf(v);
        }
      }
    }
  }
}

// ---------------- fused gather / scores / softmax / aggregate ---------------
__global__ __launch_bounds__(256) void attn_kernel(
    const int* __restrict__ masks, const int* __restrict__ begins,
    const int* __restrict__ blens, const int* __restrict__ middles,
    const int* __restrict__ mlens, const int* __restrict__ ends,
    const int* __restrict__ elens, const float* __restrict__ emb,
    const float* __restrict__ QKV, const float* __restrict__ P,
    const float* __restrict__ gates, const float* __restrict__ b_begin,
    const float* __restrict__ b_middle, const float* __restrict__ b_end,
    float* __restrict__ out, u16* __restrict__ Ebar) {
  __shared__ float bvs[3][512];
  {
    int tt = threadIdx.x;
    for (int i = tt; i < 512; i += 256) {
      bvs[0][i] = b_begin[512 + i];
      bvs[1][i] = b_middle[512 + i];
      bvs[2][i] = b_end[512 + i];
    }
  }
  __syncthreads();
  const int t = threadIdx.x;
  const int lane = t & 63;
  const int wid = t >> 6;
  const int pos = blockIdx.x * 4 + wid;
  const int mask = masks[pos];
  const float* qkv = QKV + (size_t)pos * 1536;
  float4 hv0 = *(const float4*)(qkv + 1024 + lane * 8);
  float4 hv1 = *(const float4*)(qkv + 1024 + lane * 8 + 4);
  float* orow = out + (size_t)pos * 512;
  u16* erow = Ebar + (size_t)pos * 768;

  if (mask == 0) {
    // gates all zero -> lattice keys/values exactly 0; invalid candidates have
    // score 0, valid ones -1e10.  out = w0 * hv,  Ebar row = 0.
    float4 q0 = *(const float4*)(qkv + lane * 8);
    float4 q1 = *(const float4*)(qkv + lane * 8 + 4);
    float4 k0 = *(const float4*)(qkv + 512 + lane * 8);
    float4 k1 = *(const float4*)(qkv + 512 + lane * 8 + 4);
    float p = q0.x * k0.x + q0.y * k0.y + q0.z * k0.z + q0.w * k0.w +
              q1.x * k1.x + q1.y * k1.y + q1.z * k1.z + q1.w * k1.w;
#pragma unroll
    for (int o = 32; o > 0; o >>= 1) p += __shfl_xor(p, o);
    float s0 = p;
    int nv = min(blens[pos], 5) + min(mlens[pos], 5) + min(elens[pos], 5);
    int ninv = 15 - nv;
    float w0;
    if (ninv == 0) {
      w0 = 1.f;
    } else {
      float Mx = fmaxf(s0, 0.f);
      float e0 = __expf(s0 - Mx);
      w0 = e0 / (e0 + (float)ninv * __expf(-Mx));
    }
    float4 o0, o1;
    o0.x = w0 * hv0.x; o0.y = w0 * hv0.y; o0.z = w0 * hv0.z; o0.w = w0 * hv0.w;
    o1.x = w0 * hv1.x; o1.y = w0 * hv1.y; o1.z = w0 * hv1.z; o1.w = w0 * hv1.w;
    *(float4*)(orow + lane * 8) = o0;
    *(float4*)(orow + lane * 8 + 4) = o1;
    ushort4 zz; zz.x = zz.y = zz.z = zz.w = 0;
    *(ushort4*)(erow + 0 * 256 + lane * 4) = zz;
    *(ushort4*)(erow + 1 * 256 + lane * 4) = zz;
    *(ushort4*)(erow + 2 * 256 + lane * 4) = zz;
  } else {
    float g[3];
    g[0] = gates[(size_t)pos * 3 + 0];
    g[1] = gates[(size_t)pos * 3 + 1];
    g[2] = gates[(size_t)pos * 3 + 2];
    const float* prow = P + (size_t)pos * 896;
    float4 Pt[3];
    float qb[3];
#pragma unroll
    for (int ty = 0; ty < 3; ty++) {
      Pt[ty] = *(const float4*)(prow + ty * 256 + lane * 4);
      qb[ty] = prow[768 + ty];
    }
    int lens[3] = {blens[pos], mlens[pos], elens[pos]};
    const int* ib = begins + (size_t)pos * 5;
    const int* im = middles + (size_t)pos * 5;
    const int* ie = ends + (size_t)pos * 5;
    float4 ev[3][5];
#pragma unroll
    for (int w = 0; w < 5; w++) {
      ev[0][w] = *(const float4*)(emb + (size_t)ib[w] * 256 + lane * 4);
      ev[1][w] = *(const float4*)(emb + (size_t)im[w] * 256 + lane * 4);
      ev[2][w] = *(const float4*)(emb + (size_t)ie[w] * 256 + lane * 4);
    }
    float sc[16];
    sc[0] = -1e10f;  // hidden masked when mask != 0
#pragma unroll
    for (int ty = 0; ty < 3; ty++) {
#pragma unroll
      for (int w = 0; w < 5; w++) {
        float4 e = ev[ty][w];
        float d = Pt[ty].x * e.x + Pt[ty].y * e.y + Pt[ty].z * e.z + Pt[ty].w * e.w;
#pragma unroll
        for (int o = 32; o > 0; o >>= 1) d += __shfl_xor(d, o);
        sc[1 + ty * 5 + w] = (w < lens[ty]) ? -1e10f : g[ty] * (d + qb[ty]);
      }
    }
    float Mx = sc[0];
#pragma unroll
    for (int k = 1; k < 16; k++) Mx = fmaxf(Mx, sc[k]);
    float wts[16];
    float zs = 0.f;
#pragma unroll
    for (int k = 0; k < 16; k++) {
      wts[k] = __expf(sc[k] - Mx);
      zs += wts[k];
    }
    float inv = 1.f / zs;
    float alpha[3];
#pragma unroll
    for (int ty = 0; ty < 3; ty++) {
      float ax = 0.f, ay = 0.f, az = 0.f, aw = 0.f, asum = 0.f;
#pragma unroll
      for (int w = 0; w < 5; w++) {
        float wk = wts[1 + ty * 5 + w];
        asum += wk;
        ax += wk * ev[ty][w].x;
        ay += wk * ev[ty][w].y;
        az += wk * ev[ty][w].z;
        aw += wk * ev[ty][w].w;
      }
      float sg = g[ty] * inv;
      alpha[ty] = sg * asum;
      ushort4 h;
      h.x = f2bf(ax * sg); h.y = f2bf(ay * sg); h.z = f2bf(az * sg); h.w = f2bf(aw * sg);
      *(ushort4*)(erow + ty * 256 + lane * 4) = h;
    }
    float w0 = wts[0] * inv;
    float4 o0, o1;
    int hb = lane * 8;
    o0.x = w0 * hv0.x + alpha[0] * bvs[0][hb + 0] + alpha[1] * bvs[1][hb + 0] + alpha[2] * bvs[2][hb + 0];
    o0.y = w0 * hv0.y + alpha[0] * bvs[0][hb + 1] + alpha[1] * bvs[1][hb + 1] + alpha[2] * bvs[2][hb + 1];
    o0.z = w0 * hv0.z + alpha[0] * bvs[0][hb + 2] + alpha[1] * bvs[1][hb + 2] + alpha[2] * bvs[2][hb + 2];
    o0.w = w0 * hv0.w + alpha[0] * bvs[0][hb + 3] + alpha[1] * bvs[1][hb + 3] + alpha[2] * bvs[2][hb + 3];
    o1.x = w0 * hv1.x + alpha[0] * bvs[0][hb + 4] + alpha[1] * bvs[1][hb + 4] + alpha[2] * bvs[2][hb + 4];
    o1.y = w0 * hv1.y + alpha[0] * bvs[0][hb + 5] + alpha[1] * bvs[1][hb + 5] + alpha[2] * bvs[2][hb + 5];
    o1.z = w0 * hv1.z + alpha[0] * bvs[0][hb + 6] + alpha[1] * bvs[1][hb + 6] + alpha[2] * bvs[2][hb + 6];
    o1.w = w0 * hv1.w + alpha[0] * bvs[0][hb + 7] + alpha[1] * bvs[1][hb + 7] + alpha[2] * bvs[2][hb + 7];
    *(float4*)(orow + lane * 8) = o0;
    *(float4*)(orow + lane * 8 + 4) = o1;
  }
}

// ---------------------------------------------------------------------------
extern "C" void kernel_launch(void* const* d_in, const int* in_sizes, int n_in,
                              void* d_out, int out_size, void* d_ws, size_t ws_size,
                              hipStream_t stream) {
  const float* hiddens = (const float*)d_in[0];
  const int* masks = (const int*)d_in[1];
  const int* begins = (const int*)d_in[2];
  const int* blens = (const int*)d_in[3];
  const int* middles = (const int*)d_in[4];
  const int* mlens = (const int*)d_in[5];
  const int* ends = (const int*)d_in[6];
  const int* elens = (const int*)d_in[7];
  const float* emb = (const float*)d_in[8];
  const float* Wh = (const float*)d_in[9];
  const float* bh = (const float*)d_in[10];
  const float* Wb = (const float*)d_in[11];
  const float* bb = (const float*)d_in[12];
  const float* Wm = (const float*)d_in[13];
  const float* bm = (const float*)d_in[14];
  const float* We = (const float*)d_in[15];
  const float* be = (const float*)d_in[16];
  const float* Wg = (const float*)d_in[17];
  const float* bg = (const float*)d_in[18];
  float* out = (float*)d_out;

  char* ws = (char*)d_ws;
  size_t off = 0;
  auto alloc = [&](size_t bytes) -> char* {
    char* p = ws + off;
    off += (bytes + 255) & ~(size_t)255;
    return p;
  };
  u16* Xhi = (u16*)alloc((size_t)8192 * 512 * 2);
  u16* Xlo = (u16*)alloc((size_t)8192 * 512 * 2);
  u16* WhThi = (u16*)alloc((size_t)1536 * 512 * 2);
  u16* WhTlo = (u16*)alloc((size_t)1536 * 512 * 2);
  u16* WkT = (u16*)alloc((size_t)896 * 512 * 2);
  u16* WvT = (u16*)alloc((size_t)512 * 768 * 2);
  float* QKV = (float*)alloc((size_t)8192 * 1536 * 4);
  u16* Qbf = (u16*)alloc((size_t)8192 * 512 * 2);
  float* P = (float*)alloc((size_t)8192 * 896 * 4);
  float* lmr = (float*)alloc((size_t)8192 * 9 * 4);
  float* gates = (float*)alloc((size_t)8192 * 3 * 4);
  u16* Ebar = (u16*)alloc((size_t)8192 * 768 * 2);
  if (off > ws_size) return;  // fail loudly (output stays poisoned)

  // preps
  split_x_kernel<<<4096, 256, 0, stream>>>(hiddens, Xhi, Xlo, 1048576);
  transpose_split_wh<<<dim3(8, 24), 256, 0, stream>>>(Wh, WhThi, WhTlo);
  build_wkT<<<448, 256, 0, stream>>>(Wb, Wm, We, bb, bm, be, WkT);
  build_wvT<<<dim3(4, 8, 3), 256, 0, stream>>>(Wb, Wm, We, WvT);
  lmr_kernel<<<2048, 256, 0, stream>>>(hiddens, Wg, bg, lmr);
  gates_kernel<<<32, 256, 0, stream>>>(lmr, masks, gates);

  // QKV: split-bf16 for q,hk (cols 0..1023); plain for hv (cols 1024..1535)
  gemm_mfma<true, false, true, true><<<dim3(64, 8), 256, 0, stream>>>(
      Xhi, Xlo, WhThi, WhTlo, bh, QKV, Qbf, 512, 1536, 0);
  gemm_mfma<false, false, false, true><<<dim3(64, 4), 256, 0, stream>>>(
      Xhi, nullptr, WhThi + (size_t)1024 * 512, nullptr, bh, QKV, nullptr, 512, 1536, 1024);

  // P = q(bf16) @ WkT^T   (8192 x 896)
  gemm_mfma<false, false, false, false><<<dim3(64, 7), 256, 0, stream>>>(
      Qbf, nullptr, WkT, nullptr, nullptr, P, nullptr, 512, 896, 0);

  // fused attention
  attn_kernel<<<2048, 256, 0, stream>>>(masks, begins, blens, middles, mlens, ends,
                                        elens, emb, QKV, P, gates, bb, bm, be, out, Ebar);

  // out += Ebar @ WvT^T
  gemm_mfma<false, true, false, false><<<dim3(64, 4), 256, 0, stream>>>(
      Ebar, nullptr, WvT, nullptr, nullptr, out, nullptr, 768, 512, 0);
}

// Round 2
// 315.802 us; speedup vs baseline: 1.0386x; 1.0386x over previous
//
#include <hip/hip_runtime.h>
#include <cstdint>
#include <cstddef>

// ---------------------------------------------------------------------------
// GatedLatticeLayer on MI355X.  B=16 S=512 W=5 H=512 E=256 V=100000.
// MROWS = B*S = 8192.
//
// Restructured math:
//   QKV  = X @ W_hidden + b_hidden            (8192 x 1536)  [q|hk|hv]
//   P    = q @ [Wk_b^T | Wk_m^T | Wk_e^T | bk_b bk_m bk_e]   (8192 x 771, pad 896)
//   lattice score(t,w) = g_t * (P_t . emb[idx] + qb_t)
//   ebar_t = sum_w weight * g_t * emb[idx]    (8192 x 768, bf16)
//   out = w0*hv + sum_t alpha_t*bv_t + Ebar @ [Wv_b;Wv_m;Wv_e]
// Precision: q,hk columns via split-bf16 (3-term MFMA) because s0=q.hk feeds
// softmax near-ties on mask==0 rows; everything else plain bf16 MFMA / fp32.
// Round 2: global_load_lds(16B) staging in all GEMMs, 11->6 launches, bf16 P.
// ---------------------------------------------------------------------------

typedef unsigned short u16;
typedef __attribute__((ext_vector_type(8))) short short8;
typedef __attribute__((ext_vector_type(8))) __bf16 bf16x8;
typedef __attribute__((ext_vector_type(4))) float f32x4;

#define MROWS 8192
#define SS 512

static __device__ __forceinline__ u16 f2bf(float x) {
  uint32_t u = __builtin_bit_cast(uint32_t, x);
  u += 0x7FFFu + ((u >> 16) & 1u);
  return (u16)(u >> 16);
}
static __device__ __forceinline__ float bf2f(u16 h) {
  return __builtin_bit_cast(float, (uint32_t)h << 16);
}
static __device__ __forceinline__ float sigm(float x) { return 1.f / (1.f + __expf(-x)); }

// async global->LDS 16B DMA.  LDS dest must be wave-uniform base + lane*16,
// which our thread-linear staging layout satisfies.
static __device__ __forceinline__ void gl2lds(const u16* g, u16* l) {
  __builtin_amdgcn_global_load_lds(
      (const __attribute__((address_space(1))) unsigned int*)g,
      (__attribute__((address_space(3))) unsigned int*)l, 16, 0, 0);
}

// ---------------- prep: X -> hi/lo bf16  +  lmr = X @ W_gate + b_gate -------
// 512 blocks x 256 threads; each block stages Wg once, handles 16 positions.
__global__ __launch_bounds__(256) void prep_xlmr(
    const float* __restrict__ X, const float* __restrict__ Wg,
    const float* __restrict__ bg, u16* __restrict__ hi, u16* __restrict__ lo,
    float* __restrict__ lmr) {
  __shared__ float wg[4608];
  const int t = threadIdx.x;
  for (int i = t; i < 4608; i += 256) wg[i] = Wg[i];
  __syncthreads();
  const int lane = t & 63, wid = t >> 6;
#pragma unroll
  for (int it = 0; it < 4; it++) {
    int pos = blockIdx.x * 16 + it * 4 + wid;
    const float* x = X + (size_t)pos * 512 + lane * 8;
    float4 x0 = *(const float4*)x;
    float4 x1 = *(const float4*)(x + 4);
    float xs[8] = {x0.x, x0.y, x0.z, x0.w, x1.x, x1.y, x1.z, x1.w};
    ushort4 h0, h1, l0, l1;
    h0.x = f2bf(xs[0]); l0.x = f2bf(xs[0] - bf2f(h0.x));
    h0.y = f2bf(xs[1]); l0.y = f2bf(xs[1] - bf2f(h0.y));
    h0.z = f2bf(xs[2]); l0.z = f2bf(xs[2] - bf2f(h0.z));
    h0.w = f2bf(xs[3]); l0.w = f2bf(xs[3] - bf2f(h0.w));
    h1.x = f2bf(xs[4]); l1.x = f2bf(xs[4] - bf2f(h1.x));
    h1.y = f2bf(xs[5]); l1.y = f2bf(xs[5] - bf2f(h1.y));
    h1.z = f2bf(xs[6]); l1.z = f2bf(xs[6] - bf2f(h1.z));
    h1.w = f2bf(xs[7]); l1.w = f2bf(xs[7] - bf2f(h1.w));
    ((ushort4*)hi)[pos * 128 + lane * 2] = h0;
    ((ushort4*)hi)[pos * 128 + lane * 2 + 1] = h1;
    ((ushort4*)lo)[pos * 128 + lane * 2] = l0;
    ((ushort4*)lo)[pos * 128 + lane * 2 + 1] = l1;
    float p[9];
#pragma unroll
    for (int c = 0; c < 9; c++) p[c] = 0.f;
    const float* wrow = wg + (lane * 8) * 9;
#pragma unroll
    for (int j = 0; j < 8; j++)
#pragma unroll
      for (int c = 0; c < 9; c++) p[c] += xs[j] * wrow[j * 9 + c];
#pragma unroll
    for (int c = 0; c < 9; c++)
#pragma unroll
      for (int o = 32; o > 0; o >>= 1) p[c] += __shfl_xor(p[c], o);
    if (lane == 0) {
#pragma unroll
      for (int c = 0; c < 9; c++) lmr[(size_t)pos * 9 + c] = p[c] + bg[c];
    }
  }
}

// ---------------- merged weight preps + gates -------------------------------
// blocks [0,192): W_hidden transpose+split (1536x512 hi/lo)
// blocks [192,640): WkT (896x512 bf16): rows 0..767 W_t[c][0:512], 768..770 b_t
// blocks [640,736): WvT (512x768 bf16): WvT[n][t*256+c] = W_t[c][512+n]
// blocks [736,768): gates (8192x3)  -- reads lmr from prep_xlmr (stream order)
__global__ __launch_bounds__(256) void prep_weights(
    const float* __restrict__ Wh, const float* __restrict__ Wb,
    const float* __restrict__ Wm, const float* __restrict__ We,
    const float* __restrict__ bb, const float* __restrict__ bm,
    const float* __restrict__ be, const float* __restrict__ lmr,
    const int* __restrict__ masks, u16* __restrict__ WhThi,
    u16* __restrict__ WhTlo, u16* __restrict__ WkT, u16* __restrict__ WvT,
    float* __restrict__ gates) {
  __shared__ float tile[64][65];
  const int b = blockIdx.x;
  const int t = threadIdx.x;
  if (b < 192) {
    int k0 = (b & 7) * 64;
    int n0 = (b >> 3) * 64;
#pragma unroll
    for (int i = 0; i < 16; i++) {
      int li = i * 256 + t; int r = li >> 6, c = li & 63;
      tile[r][c] = Wh[(size_t)(k0 + r) * 1536 + n0 + c];
    }
    __syncthreads();
#pragma unroll
    for (int i = 0; i < 16; i++) {
      int li = i * 256 + t; int r = li >> 6, c = li & 63;
      float v = tile[c][r];
      size_t o = (size_t)(n0 + r) * 512 + k0 + c;
      u16 h = f2bf(v);
      WhThi[o] = h;
      WhTlo[o] = f2bf(v - bf2f(h));
    }
  } else if (b < 640) {
    int tid = (b - 192) * 256 + t;      // [0, 896*128)
    int n = tid >> 7;
    int kq = (tid & 127) * 4;
    float4 v;
    if (n < 768) {
      int ty = n >> 8, c = n & 255;
      const float* src = (ty == 0 ? Wb : ty == 1 ? Wm : We) + (size_t)c * 1024 + kq;
      v = *(const float4*)src;
    } else if (n < 771) {
      int ty = n - 768;
      const float* src = (ty == 0 ? bb : ty == 1 ? bm : be) + kq;
      v = *(const float4*)src;
    } else {
      v = make_float4(0.f, 0.f, 0.f, 0.f);
    }
    ushort4 h; h.x = f2bf(v.x); h.y = f2bf(v.y); h.z = f2bf(v.z); h.w = f2bf(v.w);
    ((ushort4*)WkT)[tid] = h;
  } else if (b < 736) {
    int idx = b - 640;                  // [0,96)
    int ty = idx >> 5;
    int rem = idx & 31;
    int c0 = (rem & 3) * 64;
    int n0 = (rem >> 2) * 64;
    const float* Wsrc = ty == 0 ? Wb : ty == 1 ? Wm : We;
#pragma unroll
    for (int i = 0; i < 16; i++) {
      int li = i * 256 + t; int r = li >> 6, c = li & 63;
      tile[r][c] = Wsrc[(size_t)(c0 + r) * 1024 + 512 + n0 + c];
    }
    __syncthreads();
#pragma unroll
    for (int i = 0; i < 16; i++) {
      int li = i * 256 + t; int r = li >> 6, c = li & 63;
      WvT[(size_t)(n0 + r) * 768 + ty * 256 + c0 + c] = f2bf(tile[c][r]);
    }
  } else {
    int pos = (b - 736) * 256 + t;      // [0,8192)
    int s = pos & (SS - 1);
    float g0, g1, g2;
    if (masks[pos] == 0) {
      g0 = g1 = g2 = 0.f;
    } else if (s == 0 || s == SS - 1) {
      g0 = 1.f; g1 = 0.f; g2 = 1.f;
    } else {
      const float* p0 = lmr + (size_t)(pos - 1) * 9;
      const float* p1 = lmr + (size_t)pos * 9;
      const float* p2 = lmr + (size_t)(pos + 1) * 9;
      g0 = sigm(p0[0] + p1[3] + p2[6]);
      g1 = sigm(p0[1] + p1[4] + p2[7]);
      g2 = sigm(p0[2] + p1[5] + p2[8]);
    }
    gates[(size_t)pos * 3 + 0] = g0;
    gates[(size_t)pos * 3 + 1] = g1;
    gates[(size_t)pos * 3 + 2] = g2;
  }
}

// ---------------- MFMA GEMM: C[m,n] (+=) A(m,K) @ Bt(n,K)^T + bias ----------
// 128x128 tile, 4 waves (2x2), each wave 4x4 of 16x16x32 bf16 MFMA.
// Staging via global_load_lds width=16 (m97 structure).
// MAYSPLIT: blocks with n0 < splitN do 3-term split-bf16 accumulation.
template <bool MAYSPLIT, bool ADDOUT, bool WRITE_QBF, bool HAS_BIAS, bool OUTBF>
__global__ __launch_bounds__(256) void gemm_mfma(
    const u16* __restrict__ Ahi, const u16* __restrict__ Alo,
    const u16* __restrict__ Bhi, const u16* __restrict__ Blo,
    const float* __restrict__ bias, float* __restrict__ Cf, u16* __restrict__ Cb,
    u16* __restrict__ Qbf, int Kdim, int ldC, int splitN) {
  __shared__ __align__(16) u16 As_hi[128 * 32];
  __shared__ __align__(16) u16 Bs_hi[128 * 32];
  __shared__ __align__(16) u16 As_lo[MAYSPLIT ? 128 * 32 : 8];
  __shared__ __align__(16) u16 Bs_lo[MAYSPLIT ? 128 * 32 : 8];

  const int t = threadIdx.x;
  const int lane = t & 63;
  const int wid = t >> 6;
  const int m0 = blockIdx.x * 128;
  const int n0 = blockIdx.y * 128;
  const bool split = MAYSPLIT && (n0 < splitN);
  const int wm = (wid & 1) * 64;
  const int wn = (wid >> 1) * 64;
  const int fr = lane & 15;
  const int kq = (lane >> 4) * 8;

  f32x4 acc[4][4];
#pragma unroll
  for (int i = 0; i < 4; i++)
#pragma unroll
    for (int j = 0; j < 4; j++) acc[i][j] = (f32x4){0.f, 0.f, 0.f, 0.f};

  for (int k0 = 0; k0 < Kdim; k0 += 32) {
    __syncthreads();
#pragma unroll
    for (int p = 0; p < 2; p++) {
      int li = p * 256 + t;
      int row = li >> 2;
      int so = (li & 3) * 8;           // u16 units within the 32-wide k slab
      size_t ga = (size_t)(m0 + row) * Kdim + k0 + so;
      size_t gb = (size_t)(n0 + row) * Kdim + k0 + so;
      int ls = li * 8;                 // == row*32 + so  (16B per chunk)
      gl2lds(&Ahi[ga], &As_hi[ls]);
      gl2lds(&Bhi[gb], &Bs_hi[ls]);
      if (MAYSPLIT && split) {
        gl2lds(&Alo[ga], &As_lo[ls]);
        gl2lds(&Blo[gb], &Bs_lo[ls]);
      }
    }
    __syncthreads();
    short8 ah[4], bh[4], al[4], bl[4];
#pragma unroll
    for (int i = 0; i < 4; i++) {
      ah[i] = *(const short8*)&As_hi[(wm + i * 16 + fr) * 32 + kq];
      bh[i] = *(const short8*)&Bs_hi[(wn + i * 16 + fr) * 32 + kq];
      if (MAYSPLIT && split) {
        al[i] = *(const short8*)&As_lo[(wm + i * 16 + fr) * 32 + kq];
        bl[i] = *(const short8*)&Bs_lo[(wn + i * 16 + fr) * 32 + kq];
      }
    }
#pragma unroll
    for (int mt = 0; mt < 4; mt++)
#pragma unroll
      for (int nt = 0; nt < 4; nt++) {
        acc[mt][nt] = __builtin_amdgcn_mfma_f32_16x16x32_bf16(
            __builtin_bit_cast(bf16x8, ah[mt]), __builtin_bit_cast(bf16x8, bh[nt]),
            acc[mt][nt], 0, 0, 0);
        if (MAYSPLIT && split) {
          acc[mt][nt] = __builtin_amdgcn_mfma_f32_16x16x32_bf16(
              __builtin_bit_cast(bf16x8, al[mt]), __builtin_bit_cast(bf16x8, bh[nt]),
              acc[mt][nt], 0, 0, 0);
          acc[mt][nt] = __builtin_amdgcn_mfma_f32_16x16x32_bf16(
              __builtin_bit_cast(bf16x8, ah[mt]), __builtin_bit_cast(bf16x8, bl[nt]),
              acc[mt][nt], 0, 0, 0);
        }
      }
  }

  const int r0 = (lane >> 4) * 4;
#pragma unroll
  for (int mt = 0; mt < 4; mt++) {
#pragma unroll
    for (int nt = 0; nt < 4; nt++) {
      int col = n0 + wn + nt * 16 + fr;
      float bv = 0.f;
      if constexpr (HAS_BIAS) bv = bias[col];
#pragma unroll
      for (int r = 0; r < 4; r++) {
        int row = m0 + wm + mt * 16 + r0 + r;
        size_t off = (size_t)row * ldC + col;
        float v = acc[mt][nt][r] + bv;
        if constexpr (ADDOUT) v += Cf[off];
        if constexpr (OUTBF) Cb[off] = f2bf(v);
        else Cf[off] = v;
        if constexpr (WRITE_QBF) {
          if (col < 512) Qbf[(size_t)row * 512 + col] = f2bf(v);
        }
      }
    }
  }
}

// ---------------- fused gather / scores / softmax / aggregate ---------------
__global__ __launch_bounds__(256) void attn_kernel(
    const int* __restrict__ masks, const int* __restrict__ begins,
    const int* __restrict__ blens, const int* __restrict__ middles,
    const int* __restrict__ mlens, const int* __restrict__ ends,
    const int* __restrict__ elens, const float* __restrict__ emb,
    const float* __restrict__ QKV, const u16* __restrict__ Pb,
    const float* __restrict__ gates, const float* __restrict__ b_begin,
    const float* __restrict__ b_middle, const float* __restrict__ b_end,
    float* __restrict__ out, u16* __restrict__ Ebar) {
  __shared__ float bvs[3][512];
  {
    int tt = threadIdx.x;
    for (int i = tt; i < 512; i += 256) {
      bvs[0][i] = b_begin[512 + i];
      bvs[1][i] = b_middle[512 + i];
      bvs[2][i] = b_end[512 + i];
    }
  }
  __syncthreads();
  const int t = threadIdx.x;
  const int lane = t & 63;
  const int wid = t >> 6;
  const int pos = blockIdx.x * 4 + wid;
  const int mask = masks[pos];
  const float* qkv = QKV + (size_t)pos * 1536;
  float4 hv0 = *(const float4*)(qkv + 1024 + lane * 8);
  float4 hv1 = *(const float4*)(qkv + 1024 + lane * 8 + 4);
  float* orow = out + (size_t)pos * 512;
  u16* erow = Ebar + (size_t)pos * 768;

  if (mask == 0) {
    // gates all zero -> lattice kv exactly 0; valid candidates get -1e10,
    // invalid score 0; hidden unmasked.  out = w0*hv,  Ebar row = 0.
    float4 q0 = *(const float4*)(qkv + lane * 8);
    float4 q1 = *(const float4*)(qkv + lane * 8 + 4);
    float4 k0 = *(const float4*)(qkv + 512 + lane * 8);
    float4 k1 = *(const float4*)(qkv + 512 + lane * 8 + 4);
    float p = q0.x * k0.x + q0.y * k0.y + q0.z * k0.z + q0.w * k0.w +
              q1.x * k1.x + q1.y * k1.y + q1.z * k1.z + q1.w * k1.w;
#pragma unroll
    for (int o = 32; o > 0; o >>= 1) p += __shfl_xor(p, o);
    float s0 = p;
    int nv = min(blens[pos], 5) + min(mlens[pos], 5) + min(elens[pos], 5);
    int ninv = 15 - nv;
    float w0;
    if (ninv == 0) {
      w0 = 1.f;
    } else {
      float Mx = fmaxf(s0, 0.f);
      float e0 = __expf(s0 - Mx);
      w0 = e0 / (e0 + (float)ninv * __expf(-Mx));
    }
    float4 o0, o1;
    o0.x = w0 * hv0.x; o0.y = w0 * hv0.y; o0.z = w0 * hv0.z; o0.w = w0 * hv0.w;
    o1.x = w0 * hv1.x; o1.y = w0 * hv1.y; o1.z = w0 * hv1.z; o1.w = w0 * hv1.w;
    *(float4*)(orow + lane * 8) = o0;
    *(float4*)(orow + lane * 8 + 4) = o1;
    ushort4 zz; zz.x = zz.y = zz.z = zz.w = 0;
    *(ushort4*)(erow + 0 * 256 + lane * 4) = zz;
    *(ushort4*)(erow + 1 * 256 + lane * 4) = zz;
    *(ushort4*)(erow + 2 * 256 + lane * 4) = zz;
  } else {
    float g[3];
    g[0] = gates[(size_t)pos * 3 + 0];
    g[1] = gates[(size_t)pos * 3 + 1];
    g[2] = gates[(size_t)pos * 3 + 2];
    const u16* prow = Pb + (size_t)pos * 896;
    float4 Pt[3];
    float qb[3];
#pragma unroll
    for (int ty = 0; ty < 3; ty++) {
      ushort4 pu = *(const ushort4*)(prow + ty * 256 + lane * 4);
      Pt[ty].x = bf2f(pu.x); Pt[ty].y = bf2f(pu.y);
      Pt[ty].z = bf2f(pu.z); Pt[ty].w = bf2f(pu.w);
      qb[ty] = bf2f(prow[768 + ty]);
    }
    int lens[3] = {blens[pos], mlens[pos], elens[pos]};
    const int* ib = begins + (size_t)pos * 5;
    const int* im = middles + (size_t)pos * 5;
    const int* ie = ends + (size_t)pos * 5;
    float4 ev[3][5];
#pragma unroll
    for (int w = 0; w < 5; w++) {
      ev[0][w] = *(const float4*)(emb + (size_t)ib[w] * 256 + lane * 4);
      ev[1][w] = *(const float4*)(emb + (size_t)im[w] * 256 + lane * 4);
      ev[2][w] = *(const float4*)(emb + (size_t)ie[w] * 256 + lane * 4);
    }
    float sc[16];
    sc[0] = -1e10f;  // hidden masked when mask != 0
#pragma unroll
    for (int ty = 0; ty < 3; ty++) {
#pragma unroll
      for (int w = 0; w < 5; w++) {
        float4 e = ev[ty][w];
        float d = Pt[ty].x * e.x + Pt[ty].y * e.y + Pt[ty].z * e.z + Pt[ty].w * e.w;
#pragma unroll
        for (int o = 32; o > 0; o >>= 1) d += __shfl_xor(d, o);
        sc[1 + ty * 5 + w] = (w < lens[ty]) ? -1e10f : g[ty] * (d + qb[ty]);
      }
    }
    float Mx = sc[0];
#pragma unroll
    for (int k = 1; k < 16; k++) Mx = fmaxf(Mx, sc[k]);
    float wts[16];
    float zs = 0.f;
#pragma unroll
    for (int k = 0; k < 16; k++) {
      wts[k] = __expf(sc[k] - Mx);
      zs += wts[k];
    }
    float inv = 1.f / zs;
    float alpha[3];
#pragma unroll
    for (int ty = 0; ty < 3; ty++) {
      float ax = 0.f, ay = 0.f, az = 0.f, aw = 0.f, asum = 0.f;
#pragma unroll
      for (int w = 0; w < 5; w++) {
        float wk = wts[1 + ty * 5 + w];
        asum += wk;
        ax += wk * ev[ty][w].x;
        ay += wk * ev[ty][w].y;
        az += wk * ev[ty][w].z;
        aw += wk * ev[ty][w].w;
      }
      float sg = g[ty] * inv;
      alpha[ty] = sg * asum;
      ushort4 h;
      h.x = f2bf(ax * sg); h.y = f2bf(ay * sg); h.z = f2bf(az * sg); h.w = f2bf(aw * sg);
      *(ushort4*)(erow + ty * 256 + lane * 4) = h;
    }
    float w0 = wts[0] * inv;
    float4 o0, o1;
    int hb = lane * 8;
    o0.x = w0 * hv0.x + alpha[0] * bvs[0][hb + 0] + alpha[1] * bvs[1][hb + 0] + alpha[2] * bvs[2][hb + 0];
    o0.y = w0 * hv0.y + alpha[0] * bvs[0][hb + 1] + alpha[1] * bvs[1][hb + 1] + alpha[2] * bvs[2][hb + 1];
    o0.z = w0 * hv0.z + alpha[0] * bvs[0][hb + 2] + alpha[1] * bvs[1][hb + 2] + alpha[2] * bvs[2][hb + 2];
    o0.w = w0 * hv0.w + alpha[0] * bvs[0][hb + 3] + alpha[1] * bvs[1][hb + 3] + alpha[2] * bvs[2][hb + 3];
    o1.x = w0 * hv1.x + alpha[0] * bvs[0][hb + 4] + alpha[1] * bvs[1][hb + 4] + alpha[2] * bvs[2][hb + 4];
    o1.y = w0 * hv1.y + alpha[0] * bvs[0][hb + 5] + alpha[1] * bvs[1][hb + 5] + alpha[2] * bvs[2][hb + 5];
    o1.z = w0 * hv1.z + alpha[0] * bvs[0][hb + 6] + alpha[1] * bvs[1][hb + 6] + alpha[2] * bvs[2][hb + 6];
    o1.w = w0 * hv1.w + alpha[0] * bvs[0][hb + 7] + alpha[1] * bvs[1][hb + 7] + alpha[2] * bvs[2][hb + 7];
    *(float4*)(orow + lane * 8) = o0;
    *(float4*)(orow + lane * 8 + 4) = o1;
  }
}

// ---------------------------------------------------------------------------
extern "C" void kernel_launch(void* const* d_in, const int* in_sizes, int n_in,
                              void* d_out, int out_size, void* d_ws, size_t ws_size,
                              hipStream_t stream) {
  const float* hiddens = (const float*)d_in[0];
  const int* masks = (const int*)d_in[1];
  const int* begins = (const int*)d_in[2];
  const int* blens = (const int*)d_in[3];
  const int* middles = (const int*)d_in[4];
  const int* mlens = (const int*)d_in[5];
  const int* ends = (const int*)d_in[6];
  const int* elens = (const int*)d_in[7];
  const float* emb = (const float*)d_in[8];
  const float* Wh = (const float*)d_in[9];
  const float* bh = (const float*)d_in[10];
  const float* Wb = (const float*)d_in[11];
  const float* bb = (const float*)d_in[12];
  const float* Wm = (const float*)d_in[13];
  const float* bm = (const float*)d_in[14];
  const float* We = (const float*)d_in[15];
  const float* be = (const float*)d_in[16];
  const float* Wg = (const float*)d_in[17];
  const float* bg = (const float*)d_in[18];
  float* out = (float*)d_out;

  char* ws = (char*)d_ws;
  size_t off = 0;
  auto alloc = [&](size_t bytes) -> char* {
    char* p = ws + off;
    off += (bytes + 255) & ~(size_t)255;
    return p;
  };
  u16* Xhi = (u16*)alloc((size_t)8192 * 512 * 2);
  u16* Xlo = (u16*)alloc((size_t)8192 * 512 * 2);
  u16* WhThi = (u16*)alloc((size_t)1536 * 512 * 2);
  u16* WhTlo = (u16*)alloc((size_t)1536 * 512 * 2);
  u16* WkT = (u16*)alloc((size_t)896 * 512 * 2);
  u16* WvT = (u16*)alloc((size_t)512 * 768 * 2);
  float* QKV = (float*)alloc((size_t)8192 * 1536 * 4);
  u16* Qbf = (u16*)alloc((size_t)8192 * 512 * 2);
  u16* Pb = (u16*)alloc((size_t)8192 * 896 * 2);
  float* lmr = (float*)alloc((size_t)8192 * 9 * 4);
  float* gates = (float*)alloc((size_t)8192 * 3 * 4);
  u16* Ebar = (u16*)alloc((size_t)8192 * 768 * 2);
  if (off > ws_size) return;  // fail loudly (output stays poisoned)

  // 1) X split + lmr
  prep_xlmr<<<512, 256, 0, stream>>>(hiddens, Wg, bg, Xhi, Xlo, lmr);
  // 2) weight preps + gates (gates after lmr via stream order)
  prep_weights<<<768, 256, 0, stream>>>(Wh, Wb, Wm, We, bb, bm, be, lmr, masks,
                                        WhThi, WhTlo, WkT, WvT, gates);
  // 3) QKV: split-bf16 for q,hk (n0<1024); plain for hv
  gemm_mfma<true, false, true, true, false><<<dim3(64, 12), 256, 0, stream>>>(
      Xhi, Xlo, WhThi, WhTlo, bh, QKV, nullptr, Qbf, 512, 1536, 1024);
  // 4) P = q(bf16) @ WkT^T  -> bf16
  gemm_mfma<false, false, false, false, true><<<dim3(64, 7), 256, 0, stream>>>(
      Qbf, nullptr, WkT, nullptr, nullptr, nullptr, Pb, nullptr, 512, 896, 0);
  // 5) fused attention
  attn_kernel<<<2048, 256, 0, stream>>>(masks, begins, blens, middles, mlens, ends,
                                        elens, emb, QKV, Pb, gates, bb, bm, be, out, Ebar);
  // 6) out += Ebar @ WvT^T
  gemm_mfma<false, true, false, false, false><<<dim3(64, 4), 256, 0, stream>>>(
      Ebar, nullptr, WvT, nullptr, nullptr, out, nullptr, nullptr, 768, 512, 0);
}